// Round 1
// baseline (1704.979 us; speedup 1.0000x reference)
//
#include <hip/hip_runtime.h>
#include <hip/hip_bf16.h>

#define NEXP   8
#define MTOK   4096
#define KDIM   2048
#define NINTER 5632
#define NPAIR  8192   // MTOK * TOPK

typedef __attribute__((ext_vector_type(4))) float f32x4;
typedef __attribute__((ext_vector_type(8))) short s16x8;

__device__ __forceinline__ short f2bf(float f) {
  union { float f; unsigned u; } v; v.f = f;
  unsigned r = v.u + 0x7FFFu + ((v.u >> 16) & 1u);
  return (short)(r >> 16);
}

__device__ __forceinline__ s16x8 pack8(float4 a, float4 b) {
  s16x8 v;
  v[0] = f2bf(a.x); v[1] = f2bf(a.y); v[2] = f2bf(a.z); v[3] = f2bf(a.w);
  v[4] = f2bf(b.x); v[5] = f2bf(b.y); v[6] = f2bf(b.z); v[7] = f2bf(b.w);
  return v;
}

// ---------------- routing: deterministic counting sort of 8192 (token,slot) pairs ----------------
__global__ __launch_bounds__(512) void route_k(const int* __restrict__ ids,
                                               int* __restrict__ off,
                                               int* __restrict__ list) {
  __shared__ int sids[NPAIR];          // 32 KB
  __shared__ int scnt[64][8];
  __shared__ int sstart[64][8];
  __shared__ int s_is64;
  int tid = threadIdx.x;
  if (tid == 0) s_is64 = 1;
  __syncthreads();
  // detect int64 topk_ids: ids would be (lo,0) pairs; odd words all zero
  for (int i = tid; i < NPAIR / 2; i += 512)
    if (ids[2 * i + 1] != 0) s_is64 = 0;   // benign race, only writes 0
  __syncthreads();
  int is64 = s_is64;
  for (int i = tid; i < NPAIR; i += 512) {
    int e = is64 ? ids[2 * i] : ids[i];
    if (e < 0) e = 0; if (e > 7) e = 7;
    sids[i] = e;
  }
  if (tid < 64)
    for (int e = 0; e < 8; ++e) scnt[tid][e] = 0;
  __syncthreads();
  if (tid < 64) {
    int b0 = tid * 128;
    for (int i = 0; i < 128; ++i) ++scnt[tid][sids[b0 + i]];
  }
  __syncthreads();
  if (tid == 0) {
    int tot = 0;
    for (int e = 0; e < 8; ++e) {
      off[e] = tot;
      for (int c = 0; c < 64; ++c) { sstart[c][e] = tot; tot += scnt[c][e]; }
    }
    off[8] = tot;
  }
  __syncthreads();
  if (tid < 64) {
    int b0 = tid * 128;
    for (int i = 0; i < 128; ++i) {
      int p = b0 + i;
      int e = sids[p];
      list[sstart[tid][e]++] = p;    // stable within chunk -> fully deterministic
    }
  }
}

// ---------------- GEMM1: act[slot, 0:INTER) = silu(a1@Wg^T) * (a1@Wu^T), bf16 out ----------------
// grid (44 n-tiles, 64 m-tiles max, 8 experts), 256 threads, tile 128Mx128N(+128 up rows), BK=64
__global__ __launch_bounds__(256, 2) void gemm1_k(const float* __restrict__ a1,
                                                  const float* __restrict__ w1,
                                                  const int* __restrict__ off,
                                                  const int* __restrict__ list,
                                                  unsigned short* __restrict__ act) {
  int e = blockIdx.z, mt = blockIdx.y, nt = blockIdx.x;
  int base = off[e];
  int cnt  = off[e + 1] - base;
  if (mt * 128 >= cnt) return;
  __shared__ __align__(16) short lA[128 * 64];
  __shared__ __align__(16) short lBg[128 * 64];
  __shared__ __align__(16) short lBu[128 * 64];
  __shared__ int srow[128];
  int tid = threadIdx.x;
  if (tid < 128) {
    int r = mt * 128 + tid;
    srow[tid] = (r < cnt) ? (list[base + r] >> 1) : 0;
  }
  __syncthreads();
  int lane = tid & 63, wave = tid >> 6;
  int wm = wave >> 1, wn = wave & 1;
  int lrow = lane & 15, lhi = lane >> 4;
  f32x4 accg[4][4], accu[4][4];
#pragma unroll
  for (int i = 0; i < 4; ++i)
#pragma unroll
    for (int j = 0; j < 4; ++j) {
      accg[i][j] = (f32x4)(0.f);
      accu[i][j] = (f32x4)(0.f);
    }
  const float* w1e = w1 + (size_t)e * (2 * NINTER) * KDIM;
  int n0 = nt * 128;
  for (int k0 = 0; k0 < KDIM; k0 += 64) {
    // stage A (gathered a1 rows), fp32 -> bf16, XOR-swizzled 16B chunks
#pragma unroll
    for (int c = 0; c < 4; ++c) {
      int cid = c * 256 + tid;
      int row = cid >> 3, k8 = cid & 7;
      const float* s = a1 + (size_t)srow[row] * KDIM + k0 + k8 * 8;
      float4 f0 = *(const float4*)s;
      float4 f1 = *(const float4*)(s + 4);
      *(s16x8*)&lA[row * 64 + ((k8 ^ (row & 7)) * 8)] = pack8(f0, f1);
    }
    // stage B gate + up rows of w1[e]
#pragma unroll
    for (int c = 0; c < 4; ++c) {
      int cid = c * 256 + tid;
      int row = cid >> 3, k8 = cid & 7;
      const float* sg = w1e + (size_t)(n0 + row) * KDIM + k0 + k8 * 8;
      const float* su = w1e + (size_t)(NINTER + n0 + row) * KDIM + k0 + k8 * 8;
      float4 g0 = *(const float4*)sg;
      float4 g1 = *(const float4*)(sg + 4);
      float4 u0 = *(const float4*)su;
      float4 u1 = *(const float4*)(su + 4);
      int o = row * 64 + ((k8 ^ (row & 7)) * 8);
      *(s16x8*)&lBg[o] = pack8(g0, g1);
      *(s16x8*)&lBu[o] = pack8(u0, u1);
    }
    __syncthreads();
#pragma unroll
    for (int kk = 0; kk < 2; ++kk) {
      s16x8 af[4], bg[4], bu[4];
      int chunk = kk * 4 + lhi;
#pragma unroll
      for (int i = 0; i < 4; ++i) {
        int r = wm * 64 + i * 16 + lrow;
        af[i] = *(const s16x8*)&lA[r * 64 + ((chunk ^ (r & 7)) * 8)];
      }
#pragma unroll
      for (int j = 0; j < 4; ++j) {
        int r = wn * 64 + j * 16 + lrow;
        int o = r * 64 + ((chunk ^ (r & 7)) * 8);
        bg[j] = *(const s16x8*)&lBg[o];
        bu[j] = *(const s16x8*)&lBu[o];
      }
#pragma unroll
      for (int i = 0; i < 4; ++i)
#pragma unroll
        for (int j = 0; j < 4; ++j) {
          accg[i][j] = __builtin_amdgcn_mfma_f32_16x16x32_bf16(af[i], bg[j], accg[i][j], 0, 0, 0);
          accu[i][j] = __builtin_amdgcn_mfma_f32_16x16x32_bf16(af[i], bu[j], accu[i][j], 0, 0, 0);
        }
    }
    __syncthreads();
  }
  // epilogue: SwiGLU, write act bf16. C/D map: col = lane&15, row = (lane>>4)*4 + q
#pragma unroll
  for (int i = 0; i < 4; ++i) {
#pragma unroll
    for (int q = 0; q < 4; ++q) {
      int r = wm * 64 + i * 16 + lhi * 4 + q;
      int grow = mt * 128 + r;
      if (grow < cnt) {
        size_t rowoff = (size_t)(base + grow) * NINTER;
#pragma unroll
        for (int j = 0; j < 4; ++j) {
          float g = accg[i][j][q], u = accu[i][j][q];
          float a = (g / (1.f + __expf(-g))) * u;
          int col = n0 + wn * 64 + j * 16 + lrow;
          act[rowoff + col] = (unsigned short)f2bf(a);
        }
      }
    }
  }
}

// ---------------- GEMM2: out[token,:] += tw * (act @ w2[e]^T) ----------------
// grid (16 kout-tiles, 64 m-tiles max, 8 experts), tile 128x128, BK=64 over INTER
__global__ __launch_bounds__(256, 2) void gemm2_k(const unsigned short* __restrict__ act,
                                                  const float* __restrict__ w2,
                                                  const int* __restrict__ off,
                                                  const int* __restrict__ list,
                                                  const float* __restrict__ tw,
                                                  float* __restrict__ out) {
  int e = blockIdx.z, mt = blockIdx.y, nt = blockIdx.x;
  int base = off[e];
  int cnt  = off[e + 1] - base;
  if (mt * 128 >= cnt) return;
  __shared__ __align__(16) short lA[128 * 64];
  __shared__ __align__(16) short lB[128 * 64];
  int tid = threadIdx.x;
  int lane = tid & 63, wave = tid >> 6;
  int wm = wave >> 1, wn = wave & 1;
  int lrow = lane & 15, lhi = lane >> 4;
  f32x4 acc[4][4];
#pragma unroll
  for (int i = 0; i < 4; ++i)
#pragma unroll
    for (int j = 0; j < 4; ++j) acc[i][j] = (f32x4)(0.f);
  const float* w2e = w2 + (size_t)e * KDIM * NINTER;
  for (int k0 = 0; k0 < NINTER; k0 += 64) {
    // stage A: act rows (already bf16, contiguous slots)
#pragma unroll
    for (int c = 0; c < 4; ++c) {
      int cid = c * 256 + tid;
      int row = cid >> 3, k8 = cid & 7;
      int grow = mt * 128 + row;
      if (grow >= cnt) grow = cnt - 1;
      s16x8 v = *(const s16x8*)(act + (size_t)(base + grow) * NINTER + k0 + k8 * 8);
      *(s16x8*)&lA[row * 64 + ((k8 ^ (row & 7)) * 8)] = v;
    }
    // stage B: w2[e] rows (kout, contiguous in inter), fp32 -> bf16
#pragma unroll
    for (int c = 0; c < 4; ++c) {
      int cid = c * 256 + tid;
      int row = cid >> 3, k8 = cid & 7;
      const float* s = w2e + (size_t)(nt * 128 + row) * NINTER + k0 + k8 * 8;
      float4 f0 = *(const float4*)s;
      float4 f1 = *(const float4*)(s + 4);
      *(s16x8*)&lB[row * 64 + ((k8 ^ (row & 7)) * 8)] = pack8(f0, f1);
    }
    __syncthreads();
#pragma unroll
    for (int kk = 0; kk < 2; ++kk) {
      s16x8 af[4], bf[4];
      int chunk = kk * 4 + lhi;
#pragma unroll
      for (int i = 0; i < 4; ++i) {
        int r = wm * 64 + i * 16 + lrow;
        af[i] = *(const s16x8*)&lA[r * 64 + ((chunk ^ (r & 7)) * 8)];
      }
#pragma unroll
      for (int j = 0; j < 4; ++j) {
        int r = wn * 64 + j * 16 + lrow;
        bf[j] = *(const s16x8*)&lB[r * 64 + ((chunk ^ (r & 7)) * 8)];
      }
#pragma unroll
      for (int i = 0; i < 4; ++i)
#pragma unroll
        for (int j = 0; j < 4; ++j)
          acc[i][j] = __builtin_amdgcn_mfma_f32_16x16x32_bf16(af[i], bf[j], acc[i][j], 0, 0, 0);
    }
    __syncthreads();
  }
  // epilogue: weighted atomic scatter into out
#pragma unroll
  for (int i = 0; i < 4; ++i) {
#pragma unroll
    for (int q = 0; q < 4; ++q) {
      int r = wm * 64 + i * 16 + lhi * 4 + q;
      int grow = mt * 128 + r;
      if (grow < cnt) {
        int p = list[base + grow];
        int m = p >> 1;
        float wgt = tw[p];
#pragma unroll
        for (int j = 0; j < 4; ++j) {
          int col = nt * 128 + wn * 64 + j * 16 + lrow;
          atomicAdd(&out[(size_t)m * KDIM + col], wgt * acc[i][j][q]);
        }
      }
    }
  }
}

extern "C" void kernel_launch(void* const* d_in, const int* in_sizes, int n_in,
                              void* d_out, int out_size, void* d_ws, size_t ws_size,
                              hipStream_t stream) {
  const float* a1 = (const float*)d_in[0];
  const float* w1 = (const float*)d_in[1];
  const float* w2 = (const float*)d_in[2];
  const float* tw = (const float*)d_in[3];
  const int*   ids = (const int*)d_in[4];
  float* out = (float*)d_out;

  int* off  = (int*)d_ws;                                   // 16 ints
  int* list = off + 16;                                     // 8192 ints
  unsigned short* act = (unsigned short*)((char*)d_ws + 65536);  // [8192][5632] bf16, ~92 MB

  hipMemsetAsync(d_out, 0, (size_t)MTOK * KDIM * sizeof(float), stream);
  route_k<<<1, 512, 0, stream>>>(ids, off, list);
  gemm1_k<<<dim3(NINTER / 128, 64, NEXP), 256, 0, stream>>>(a1, w1, off, list, act);
  gemm2_k<<<dim3(KDIM / 128, 64, NEXP), 256, 0, stream>>>(act, w2, off, list, tw, out);
}

// Round 2
// 1047.467 us; speedup vs baseline: 1.6277x; 1.6277x over previous
//
#include <hip/hip_runtime.h>
#include <hip/hip_bf16.h>

#define NEXP   8
#define MTOK   4096
#define KDIM   2048
#define NINTER 5632
#define NPAIR  8192   // MTOK * TOPK

#define AS3 __attribute__((address_space(3)))
#define AS1 __attribute__((address_space(1)))

typedef __attribute__((ext_vector_type(4))) float f32x4;
typedef __attribute__((ext_vector_type(8))) short s16x8;

__device__ __forceinline__ short f2bf(float f) {
  union { float f; unsigned u; } v; v.f = f;
  unsigned r = v.u + 0x7FFFu + ((v.u >> 16) & 1u);
  return (short)(r >> 16);
}

__device__ __forceinline__ s16x8 pack8(float4 a, float4 b) {
  s16x8 v;
  v[0] = f2bf(a.x); v[1] = f2bf(a.y); v[2] = f2bf(a.z); v[3] = f2bf(a.w);
  v[4] = f2bf(b.x); v[5] = f2bf(b.y); v[6] = f2bf(b.z); v[7] = f2bf(b.w);
  return v;
}

// ---------------- fp32 -> bf16 one-shot conversion (grid-stride, 8 elem/thread) ----------------
__global__ __launch_bounds__(256) void cvt_k(const float* __restrict__ src,
                                             unsigned short* __restrict__ dst, size_t n8) {
  size_t i = (size_t)blockIdx.x * blockDim.x + threadIdx.x;
  size_t stride = (size_t)gridDim.x * blockDim.x;
  for (; i < n8; i += stride) {
    const float4* p = (const float4*)(src + i * 8);
    float4 f0 = p[0], f1 = p[1];
    *(s16x8*)(dst + i * 8) = pack8(f0, f1);
  }
}

// ---------------- routing: deterministic counting sort of 8192 (token,slot) pairs ----------------
__global__ __launch_bounds__(512) void route_k(const int* __restrict__ ids,
                                               int* __restrict__ off,
                                               int* __restrict__ list) {
  __shared__ int sids[NPAIR];
  __shared__ int scnt[64][8];
  __shared__ int sstart[64][8];
  __shared__ int s_is64;
  int tid = threadIdx.x;
  if (tid == 0) s_is64 = 1;
  __syncthreads();
  for (int i = tid; i < NPAIR / 2; i += 512)
    if (ids[2 * i + 1] != 0) s_is64 = 0;
  __syncthreads();
  int is64 = s_is64;
  for (int i = tid; i < NPAIR; i += 512) {
    int e = is64 ? ids[2 * i] : ids[i];
    if (e < 0) e = 0; if (e > 7) e = 7;
    sids[i] = e;
  }
  if (tid < 64)
    for (int e = 0; e < 8; ++e) scnt[tid][e] = 0;
  __syncthreads();
  if (tid < 64) {
    int b0 = tid * 128;
    for (int i = 0; i < 128; ++i) ++scnt[tid][sids[b0 + i]];
  }
  __syncthreads();
  if (tid == 0) {
    int tot = 0;
    for (int e = 0; e < 8; ++e) {
      off[e] = tot;
      for (int c = 0; c < 64; ++c) { sstart[c][e] = tot; tot += scnt[c][e]; }
    }
    off[8] = tot;
  }
  __syncthreads();
  if (tid < 64) {
    int b0 = tid * 128;
    for (int i = 0; i < 128; ++i) {
      int p = b0 + i;
      int e = sids[p];
      list[sstart[tid][e]++] = p;
    }
  }
}

// ---------------- GEMM1: act[slot,:] = silu(a1@Wg^T) * (a1@Wu^T) ----------------
// BF=1: bf16 sources, global_load_lds staging. BF=0: fp32 sources, in-loop cvt.
template <int BF>
__global__ __launch_bounds__(256, 2) void gemm1_t(const float* __restrict__ a1,
                                                  const unsigned short* __restrict__ a1b,
                                                  const float* __restrict__ w1,
                                                  const unsigned short* __restrict__ w1b,
                                                  const int* __restrict__ off,
                                                  const int* __restrict__ list,
                                                  unsigned short* __restrict__ act) {
  int e = blockIdx.z, mt = blockIdx.y, nt = blockIdx.x;
  int base = off[e];
  int cnt  = off[e + 1] - base;
  if (mt * 128 >= cnt) return;
  __shared__ __align__(16) short lA[128 * 64];
  __shared__ __align__(16) short lBg[128 * 64];
  __shared__ __align__(16) short lBu[128 * 64];
  __shared__ int srow[128];
  int tid = threadIdx.x;
  if (tid < 128) {
    int r = mt * 128 + tid;
    srow[tid] = (r < cnt) ? (list[base + r] >> 1) : 0;
  }
  __syncthreads();
  int lane = tid & 63, wave = tid >> 6;
  int wm = wave >> 1, wn = wave & 1;
  int lrow = lane & 15, lhi = lane >> 4;
  f32x4 accg[4][4], accu[4][4];
#pragma unroll
  for (int i = 0; i < 4; ++i)
#pragma unroll
    for (int j = 0; j < 4; ++j) { accg[i][j] = (f32x4)(0.f); accu[i][j] = (f32x4)(0.f); }
  int n0 = nt * 128;

  // BF path: per-wave staging bases (wave stages rows [wave*32, wave*32+32))
  const unsigned short* aSrc[4];
  const unsigned short* gSrc[4];
  const unsigned short* uSrc[4];
  if constexpr (BF) {
    const unsigned short* w1be = w1b + (size_t)e * (2 * NINTER) * KDIM;
    int c = lane & 7;
#pragma unroll
    for (int q = 0; q < 4; ++q) {
      int r = wave * 32 + q * 8 + (lane >> 3);       // LDS row this lane feeds
      int swz = (c ^ (r & 7)) * 8;                   // pre-swizzled source chunk
      aSrc[q] = a1b + (size_t)srow[r] * KDIM + swz;
      gSrc[q] = w1be + (size_t)(n0 + r) * KDIM + swz;
      uSrc[q] = w1be + (size_t)(NINTER + n0 + r) * KDIM + swz;
    }
  }
  const float* w1e = w1 + (size_t)e * (2 * NINTER) * KDIM;

  for (int k0 = 0; k0 < KDIM; k0 += 64) {
    if constexpr (BF) {
#pragma unroll
      for (int q = 0; q < 4; ++q) {
        int row0 = wave * 32 + q * 8;
        __builtin_amdgcn_global_load_lds((const AS1 void*)(aSrc[q] + k0), (AS3 void*)&lA[row0 * 64], 16, 0, 0);
        __builtin_amdgcn_global_load_lds((const AS1 void*)(gSrc[q] + k0), (AS3 void*)&lBg[row0 * 64], 16, 0, 0);
        __builtin_amdgcn_global_load_lds((const AS1 void*)(uSrc[q] + k0), (AS3 void*)&lBu[row0 * 64], 16, 0, 0);
      }
    } else {
#pragma unroll
      for (int c4 = 0; c4 < 4; ++c4) {
        int cid = c4 * 256 + tid;
        int row = cid >> 3, k8 = cid & 7;
        const float* s = a1 + (size_t)srow[row] * KDIM + k0 + k8 * 8;
        float4 f0 = *(const float4*)s;
        float4 f1 = *(const float4*)(s + 4);
        *(s16x8*)&lA[row * 64 + ((k8 ^ (row & 7)) * 8)] = pack8(f0, f1);
      }
#pragma unroll
      for (int c4 = 0; c4 < 4; ++c4) {
        int cid = c4 * 256 + tid;
        int row = cid >> 3, k8 = cid & 7;
        const float* sg = w1e + (size_t)(n0 + row) * KDIM + k0 + k8 * 8;
        const float* su = w1e + (size_t)(NINTER + n0 + row) * KDIM + k0 + k8 * 8;
        float4 g0 = *(const float4*)sg;
        float4 g1 = *(const float4*)(sg + 4);
        float4 u0 = *(const float4*)su;
        float4 u1 = *(const float4*)(su + 4);
        int o = row * 64 + ((k8 ^ (row & 7)) * 8);
        *(s16x8*)&lBg[o] = pack8(g0, g1);
        *(s16x8*)&lBu[o] = pack8(u0, u1);
      }
    }
    __syncthreads();
#pragma unroll
    for (int kk = 0; kk < 2; ++kk) {
      s16x8 af[4], bg[4], bu[4];
      int chunk = kk * 4 + lhi;
#pragma unroll
      for (int i = 0; i < 4; ++i) {
        int r = wm * 64 + i * 16 + lrow;
        af[i] = *(const s16x8*)&lA[r * 64 + ((chunk ^ (r & 7)) * 8)];
      }
#pragma unroll
      for (int j = 0; j < 4; ++j) {
        int r = wn * 64 + j * 16 + lrow;
        int o = r * 64 + ((chunk ^ (r & 7)) * 8);
        bg[j] = *(const s16x8*)&lBg[o];
        bu[j] = *(const s16x8*)&lBu[o];
      }
#pragma unroll
      for (int i = 0; i < 4; ++i)
#pragma unroll
        for (int j = 0; j < 4; ++j) {
          accg[i][j] = __builtin_amdgcn_mfma_f32_16x16x32_bf16(af[i], bg[j], accg[i][j], 0, 0, 0);
          accu[i][j] = __builtin_amdgcn_mfma_f32_16x16x32_bf16(af[i], bu[j], accu[i][j], 0, 0, 0);
        }
    }
    __syncthreads();
  }
#pragma unroll
  for (int i = 0; i < 4; ++i) {
#pragma unroll
    for (int q = 0; q < 4; ++q) {
      int r = wm * 64 + i * 16 + lhi * 4 + q;
      int grow = mt * 128 + r;
      if (grow < cnt) {
        size_t rowoff = (size_t)(base + grow) * NINTER;
#pragma unroll
        for (int j = 0; j < 4; ++j) {
          float g = accg[i][j][q], u = accu[i][j][q];
          float a = (g / (1.f + __expf(-g))) * u;
          int col = n0 + wn * 64 + j * 16 + lrow;
          act[rowoff + col] = (unsigned short)f2bf(a);
        }
      }
    }
  }
}

// ---------------- GEMM2: out[token,:] += tw * (act @ w2[e]^T) ----------------
template <int BF>
__global__ __launch_bounds__(256, 2) void gemm2_t(const unsigned short* __restrict__ act,
                                                  const float* __restrict__ w2,
                                                  const unsigned short* __restrict__ w2b,
                                                  const int* __restrict__ off,
                                                  const int* __restrict__ list,
                                                  const float* __restrict__ tw,
                                                  float* __restrict__ out) {
  int e = blockIdx.z, mt = blockIdx.y, nt = blockIdx.x;
  int base = off[e];
  int cnt  = off[e + 1] - base;
  if (mt * 128 >= cnt) return;
  __shared__ __align__(16) short lA[128 * 64];
  __shared__ __align__(16) short lB[128 * 64];
  int tid = threadIdx.x;
  int lane = tid & 63, wave = tid >> 6;
  int wm = wave >> 1, wn = wave & 1;
  int lrow = lane & 15, lhi = lane >> 4;
  f32x4 acc[4][4];
#pragma unroll
  for (int i = 0; i < 4; ++i)
#pragma unroll
    for (int j = 0; j < 4; ++j) acc[i][j] = (f32x4)(0.f);
  const float* w2e = w2 + (size_t)e * KDIM * NINTER;

  const unsigned short* aSrc[4];
  const unsigned short* bSrc[4];
  if constexpr (BF) {
    const unsigned short* w2be = w2b + (size_t)e * KDIM * NINTER;
    int c = lane & 7;
#pragma unroll
    for (int q = 0; q < 4; ++q) {
      int r = wave * 32 + q * 8 + (lane >> 3);
      int swz = (c ^ (r & 7)) * 8;
      int grow = mt * 128 + r;
      if (grow >= cnt) grow = cnt - 1;
      aSrc[q] = act + (size_t)(base + grow) * NINTER + swz;
      bSrc[q] = w2be + (size_t)(nt * 128 + r) * NINTER + swz;
    }
  }

  for (int k0 = 0; k0 < NINTER; k0 += 64) {
    if constexpr (BF) {
#pragma unroll
      for (int q = 0; q < 4; ++q) {
        int row0 = wave * 32 + q * 8;
        __builtin_amdgcn_global_load_lds((const AS1 void*)(aSrc[q] + k0), (AS3 void*)&lA[row0 * 64], 16, 0, 0);
        __builtin_amdgcn_global_load_lds((const AS1 void*)(bSrc[q] + k0), (AS3 void*)&lB[row0 * 64], 16, 0, 0);
      }
    } else {
#pragma unroll
      for (int c4 = 0; c4 < 4; ++c4) {
        int cid = c4 * 256 + tid;
        int row = cid >> 3, k8 = cid & 7;
        int grow = mt * 128 + row;
        if (grow >= cnt) grow = cnt - 1;
        s16x8 v = *(const s16x8*)(act + (size_t)(base + grow) * NINTER + k0 + k8 * 8);
        *(s16x8*)&lA[row * 64 + ((k8 ^ (row & 7)) * 8)] = v;
      }
#pragma unroll
      for (int c4 = 0; c4 < 4; ++c4) {
        int cid = c4 * 256 + tid;
        int row = cid >> 3, k8 = cid & 7;
        const float* s = w2e + (size_t)(nt * 128 + row) * NINTER + k0 + k8 * 8;
        float4 f0 = *(const float4*)s;
        float4 f1 = *(const float4*)(s + 4);
        *(s16x8*)&lB[row * 64 + ((k8 ^ (row & 7)) * 8)] = pack8(f0, f1);
      }
    }
    __syncthreads();
#pragma unroll
    for (int kk = 0; kk < 2; ++kk) {
      s16x8 af[4], bf[4];
      int chunk = kk * 4 + lhi;
#pragma unroll
      for (int i = 0; i < 4; ++i) {
        int r = wm * 64 + i * 16 + lrow;
        af[i] = *(const s16x8*)&lA[r * 64 + ((chunk ^ (r & 7)) * 8)];
      }
#pragma unroll
      for (int j = 0; j < 4; ++j) {
        int r = wn * 64 + j * 16 + lrow;
        bf[j] = *(const s16x8*)&lB[r * 64 + ((chunk ^ (r & 7)) * 8)];
      }
#pragma unroll
      for (int i = 0; i < 4; ++i)
#pragma unroll
        for (int j = 0; j < 4; ++j)
          acc[i][j] = __builtin_amdgcn_mfma_f32_16x16x32_bf16(af[i], bf[j], acc[i][j], 0, 0, 0);
    }
    __syncthreads();
  }
#pragma unroll
  for (int i = 0; i < 4; ++i) {
#pragma unroll
    for (int q = 0; q < 4; ++q) {
      int r = wm * 64 + i * 16 + lhi * 4 + q;
      int grow = mt * 128 + r;
      if (grow < cnt) {
        int p = list[base + grow];
        int m = p >> 1;
        float wgt = tw[p];
#pragma unroll
        for (int j = 0; j < 4; ++j) {
          int col = nt * 128 + wn * 64 + j * 16 + lrow;
          atomicAdd(&out[(size_t)m * KDIM + col], wgt * acc[i][j][q]);
        }
      }
    }
  }
}

extern "C" void kernel_launch(void* const* d_in, const int* in_sizes, int n_in,
                              void* d_out, int out_size, void* d_ws, size_t ws_size,
                              hipStream_t stream) {
  const float* a1 = (const float*)d_in[0];
  const float* w1 = (const float*)d_in[1];
  const float* w2 = (const float*)d_in[2];
  const float* tw = (const float*)d_in[3];
  const int*   ids = (const int*)d_in[4];
  float* out = (float*)d_out;

  // ws layout
  int* off  = (int*)d_ws;                                        // 16 ints
  int* list = off + 16;                                          // 8192 ints
  unsigned short* act = (unsigned short*)((char*)d_ws + 65536);  // 92,274,688 B
  size_t actB = (size_t)NPAIR * NINTER * 2;
  unsigned short* a1b = (unsigned short*)((char*)act + actB);        // 16,777,216 B
  size_t a1B = (size_t)MTOK * KDIM * 2;
  unsigned short* w1b = (unsigned short*)((char*)a1b + a1B);         // 369,098,752 B
  size_t w1B = (size_t)NEXP * 2 * NINTER * KDIM * 2;
  unsigned short* w2b = (unsigned short*)((char*)w1b + w1B);         // 184,549,376 B
  size_t w2B = (size_t)NEXP * KDIM * NINTER * 2;
  size_t need = 65536 + actB + a1B + w1B + w2B;

  hipMemsetAsync(d_out, 0, (size_t)MTOK * KDIM * sizeof(float), stream);
  route_k<<<1, 512, 0, stream>>>(ids, off, list);

  if (ws_size >= need) {
    cvt_k<<<2048, 256, 0, stream>>>(a1, a1b, a1B / 16);
    cvt_k<<<2048, 256, 0, stream>>>(w1, w1b, w1B / 16);
    cvt_k<<<2048, 256, 0, stream>>>(w2, w2b, w2B / 16);
    gemm1_t<1><<<dim3(NINTER / 128, 64, NEXP), 256, 0, stream>>>(a1, a1b, w1, w1b, off, list, act);
    gemm2_t<1><<<dim3(KDIM / 128, 64, NEXP), 256, 0, stream>>>(act, w2, w2b, off, list, tw, out);
  } else {
    gemm1_t<0><<<dim3(NINTER / 128, 64, NEXP), 256, 0, stream>>>(a1, a1b, w1, w1b, off, list, act);
    gemm2_t<0><<<dim3(KDIM / 128, 64, NEXP), 256, 0, stream>>>(act, w2, w2b, off, list, tw, out);
  }
}